// Round 1
// baseline (320.734 us; speedup 1.0000x reference)
//
#include <hip/hip_runtime.h>
#include <stdint.h>

// Problem constants
#define B 8
#define N 2048
#define D 16
#define KNN 32
#define DM 256
#define CAP 96   // tie-fixup cap; degenerate all-tie batches still rank correctly

// ---------------------------------------------------------------------------
// K1: fused prep (round-5 PROVEN, verbatim). Blocks 0..63: own-batch fp64
// stats, then per-point masked x_crd row -> xcrd, sq, Tc/Tf.
// Block 64: W transpose + pe bias/loss.
// ---------------------------------------------------------------------------
__global__ __launch_bounds__(256) void knn_prep(
    const float* __restrict__ x, const float* __restrict__ features,
    const float* __restrict__ Wc, const float* __restrict__ Wf,
    const float* __restrict__ pec, const float* __restrict__ pef,
    float* __restrict__ xcrd, float* __restrict__ sq,
    float* __restrict__ Tc, float* __restrict__ Tf,
    float* __restrict__ WcT, float* __restrict__ WfT,
    float* __restrict__ cbias, float* __restrict__ pe_loss_out)
{
    if (blockIdx.x == 64) {
        int dm = threadIdx.x;
        float cb = 0.f, al = 0.f;
#pragma unroll
        for (int p = 0; p < D; ++p)
            cb += pec[p * DM + dm] + pef[p * DM + dm];
#pragma unroll
        for (int p = 0; p < D; ++p)
            al += fabsf(pec[p * DM + dm]) + fabsf(pef[p * DM + dm]);
        cbias[dm] = cb;
#pragma unroll
        for (int k = 0; k < KNN; ++k) {
            WcT[k * DM + dm] = Wc[dm * KNN + k];
            WfT[k * DM + dm] = Wf[dm * KNN + k];
        }
        __shared__ float redf[256];
        redf[dm] = al; __syncthreads();
        for (int st = 128; st > 0; st >>= 1) {
            if (dm < st) redf[dm] += redf[dm + st];
            __syncthreads();
        }
        if (dm == 0) pe_loss_out[0] = redf[0];
        return;
    }

    int tid = threadIdx.x;
    int b = blockIdx.x >> 3;

    // ---- own-batch stats: 8 rows per thread, fp64 accumulate ----
    double ls[D], lq[D];
#pragma unroll
    for (int d = 0; d < D; ++d) { ls[d] = 0.0; lq[d] = 0.0; }
    for (int r = 0; r < 8; ++r) {
        const float* row = x + ((size_t)b * N + r * 256 + tid) * D;
#pragma unroll
        for (int d = 0; d < D; d += 4) {
            float4 v = *(const float4*)(row + d);
            double x0 = v.x, x1 = v.y, x2 = v.z, x3 = v.w;
            ls[d]   += x0; lq[d]   += x0 * x0;
            ls[d+1] += x1; lq[d+1] += x1 * x1;
            ls[d+2] += x2; lq[d+2] += x2 * x2;
            ls[d+3] += x3; lq[d+3] += x3 * x3;
        }
    }
#pragma unroll
    for (int d = 0; d < D; ++d) {
        double s = ls[d], q = lq[d];
#pragma unroll
        for (int st = 32; st >= 1; st >>= 1) {
            s += __shfl_xor(s, st, 64);
            q += __shfl_xor(q, st, 64);
        }
        ls[d] = s; lq[d] = q;
    }
    __shared__ double sred[4][2 * D];
    __shared__ float smean[32], sscale[32];
    int wave = tid >> 6, lane = tid & 63;
    if (lane == 0) {
#pragma unroll
        for (int d = 0; d < D; ++d) {
            sred[wave][d]     = ls[d];
            sred[wave][D + d] = lq[d];
        }
    }
    __syncthreads();
    if (tid < D) {
        int d = tid;
        double S = sred[0][d] + sred[1][d] + sred[2][d] + sred[3][d];
        double Q = sred[0][D+d] + sred[1][D+d] + sred[2][D+d] + sred[3][D+d];
        double mean = S / (double)N;
        double var  = (Q - S * S / (double)N) / (double)(N - 1);
        if (var < 0.0) var = 0.0;
        float stdv = (float)sqrt(var);
        float scl  = 1.0f / (stdv + 1e-5f);
        float scl0 = 1.0f / (0.0f + 1e-5f);
        bool mask = features[b * D + d] > 0.1f;
        smean [d]      = mask ? 0.0f : (float)mean;
        sscale[d]      = mask ? scl0 : scl;
        smean [16 + d] = mask ? (float)mean : 0.0f;
        sscale[16 + d] = mask ? scl : scl0;
    }
    __syncthreads();

    // ---- per-point processing (identical arithmetic to rounds 1-5) ----
    int t = blockIdx.x * 256 + tid;
    float tc = 0.f, tf = 0.f, s = 0.f;
    float row[D];
#pragma unroll
    for (int d = 0; d < D; ++d) {
        float xv = x[(size_t)t * D + d];
        bool mask = features[b * D + d] > 0.1f;
        float xc = mask ? 0.f : xv;
        float xf = mask ? xv : 0.f;
        row[d] = xc;
        s += xc * xc;                            // sequential, mirrors ref sq
        float vc = (xc - smean[d])      * sscale[d];
        vc = fminf(10.f, fmaxf(-10.f, vc));
        float vf = (xf - smean[16 + d]) * sscale[16 + d];
        vf = fminf(10.f, fmaxf(-10.f, vf));
        tc += vc; tf += vf;
    }
#pragma unroll
    for (int d = 0; d < D; d += 4)
        *(float4*)(xcrd + (size_t)t * D + d) =
            make_float4(row[d], row[d+1], row[d+2], row[d+3]);
    sq[t] = s; Tc[t] = tc; Tf[t] = tf;
}

// ---------------------------------------------------------------------------
// K2: FOUR waves per block (one query per wave) to lift occupancy past the
// 1-wave-workgroup residency cap (was ~10 waves/CU, VALUBusy 62%).  Each
// wave's fill/selection/fixup arithmetic is byte-identical to the proven
// round-5 version.  collect[]/sortedm[] are per-wave LDS slices; the
// producer and consumer of each slice is the SAME wave, so block barriers
// are replaced by wave-local s_waitcnt lgkmcnt(0) fences (lockstep wave64
// makes this exact), keeping the 4 waves fully independent for latency
// hiding.
// ---------------------------------------------------------------------------
#define WAVE_LDS_FENCE() do {                                   \
    asm volatile("s_waitcnt lgkmcnt(0)" ::: "memory");          \
    __builtin_amdgcn_sched_barrier(0);                          \
} while (0)

__global__ __launch_bounds__(256, 5) void knn_main(
    const float* __restrict__ xcrd, const float* __restrict__ sq,
    const float* __restrict__ Tc, const float* __restrict__ Tf,
    const float* __restrict__ WcT, const float* __restrict__ WfT,
    const float* __restrict__ cbias, float* __restrict__ out)
{
    __shared__ unsigned long long collect[4][CAP];
    __shared__ int sortedm[4][KNN];

    const int lane = threadIdx.x & 63;
    const int wid  = threadIdx.x >> 6;
    const int qid  = (blockIdx.x << 2) | wid;    // 0..16383
    const int b = qid >> 11;
    const int n = qid & (N - 1);

    unsigned long long* wcollect = collect[wid];
    int* wsorted = sortedm[wid];

    const float* xb  = xcrd + (size_t)b * N * D;
    const float* sqb = sq + b * N;

    // query row
    float qx[D];
#pragma unroll
    for (int d = 0; d < D; d += 4) {
        float4 v = *(const float4*)(xb + (size_t)n * D + d);
        qx[d] = v.x; qx[d+1] = v.y; qx[d+2] = v.z; qx[d+3] = v.w;
    }
    const float sqn = sqb[n];

    // ---- fill: round-5 distance arithmetic, byte-identical ----
    float orig[KNN], srt[KNN];
#pragma unroll
    for (int j = 0; j < KNN; ++j) {
        int m = j * 64 + lane;
        const float* xm = xb + (size_t)m * D;
        float4 v0 = *(const float4*)(xm);
        float4 v1 = *(const float4*)(xm + 4);
        float4 v2 = *(const float4*)(xm + 8);
        float4 v3 = *(const float4*)(xm + 12);
        float dot = 0.f;
        dot += qx[0]  * v0.x; dot += qx[1]  * v0.y;
        dot += qx[2]  * v0.z; dot += qx[3]  * v0.w;
        dot += qx[4]  * v1.x; dot += qx[5]  * v1.y;
        dot += qx[6]  * v1.z; dot += qx[7]  * v1.w;
        dot += qx[8]  * v2.x; dot += qx[9]  * v2.y;
        dot += qx[10] * v2.z; dot += qx[11] * v2.w;
        dot += qx[12] * v3.x; dot += qx[13] * v3.y;
        dot += qx[14] * v3.z; dot += qx[15] * v3.w;
        float d2 = sqn + sqb[m] - 2.0f * dot;
        float dist = fabsf(sqrtf(fmaxf(d2, 0.f)));   // fabs: -0 -> +0
        orig[j] = dist; srt[j] = dist;
    }

    // ---- per-lane bitonic sort (ascending) of the value copy ----
#pragma unroll
    for (int kk = 2; kk <= KNN; kk <<= 1) {
#pragma unroll
        for (int jj = kk >> 1; jj > 0; jj >>= 1) {
#pragma unroll
            for (int i = 0; i < KNN; ++i) {
                int l = i ^ jj;
                if (l > i) {
                    float a = srt[i], c2 = srt[l];
                    if ((i & kk) == 0) { srt[i] = fminf(a, c2); srt[l] = fmaxf(a, c2); }
                    else               { srt[i] = fmaxf(a, c2); srt[l] = fminf(a, c2); }
                }
            }
        }
    }

    // ---- 6 butterfly min-32 merge rounds (values only, duplicates ok) ----
#pragma unroll 1
    for (int s = 1; s <= 32; s <<= 1) {
#pragma unroll
        for (int i = 0; i < KNN / 2; ++i) {
            int r = KNN - 1 - i;
            float o_i = __shfl_xor(srt[r], s, 64);   // partner[31-i]
            float o_r = __shfl_xor(srt[i], s, 64);   // partner[31-r]
            srt[i] = fminf(srt[i], o_i);
            srt[r] = fminf(srt[r], o_r);
        }
#pragma unroll
        for (int jj = 16; jj >= 1; jj >>= 1) {
#pragma unroll
            for (int i = 0; i < KNN; ++i) {
                if ((i & jj) == 0) {
                    int l = i + jj;
                    float a = srt[i], c2 = srt[l];
                    srt[i] = fminf(a, c2);
                    srt[l] = fmaxf(a, c2);
                }
            }
        }
    }
    const float tau = srt[31];                   // exact 32nd smallest value

    // ---- tie-fixup: compact all dist <= tau in ascending global-index order ----
    const unsigned long long lmask = (1ULL << lane) - 1ULL;
    int base = 0;
#pragma unroll
    for (int j = 0; j < KNN; ++j) {
        bool f = (orig[j] <= tau);
        unsigned long long mk = __ballot(f);
        if (f) {
            int pos = base + (int)__popcll(mk & lmask);
            if (pos < CAP)
                wcollect[pos] =
                    (((unsigned long long)__float_as_uint(orig[j])) << 11)
                    | (unsigned)(j * 64 + lane);
        }
        base += (int)__popcll(mk);
    }
    int T = base < CAP ? base : CAP;             // wave-uniform, >= 32
    WAVE_LDS_FENCE();                            // all lanes' ds_writes drained

    // ---- rank the T collected items (keys globally unique) ----
#pragma unroll 1
    for (int slot = 0; slot < 2; ++slot) {
        int i = lane + slot * 64;
        if (i < T) {
            unsigned long long mk = wcollect[i];
            int rank = 0;
#pragma unroll 1
            for (int t2 = 0; t2 < T; ++t2)
                rank += (wcollect[t2] < mk) ? 1 : 0;
            if (rank < KNN)
                wsorted[rank] = (int)(mk & 2047u);
        }
    }
    WAVE_LDS_FENCE();                            // wsorted visible to own wave

    // ---- matvec: ranked top-32 ----
    float acc[4] = {0.f, 0.f, 0.f, 0.f};
    const float* Tcb = Tc + b * N;
    const float* Tfb = Tf + b * N;
    const float Tcn = Tcb[n], Tfn = Tfb[n];

#pragma unroll
    for (int k = 0; k < KNN; ++k) {
        int wm = wsorted[k];
        float ak = Tcb[wm] - Tcn;
        float bk = Tfb[wm] - Tfn;
        const float* wc = WcT + k * DM + lane;
        const float* wf = WfT + k * DM + lane;
#pragma unroll
        for (int q = 0; q < 4; ++q)
            acc[q] += wc[q * 64] * ak + wf[q * 64] * bk;
    }

    size_t obase = (size_t)qid * DM + lane;
#pragma unroll
    for (int q = 0; q < 4; ++q)
        out[obase + q * 64] = acc[q] + cbias[lane + q * 64];
}

// ---------------------------------------------------------------------------
extern "C" void kernel_launch(void* const* d_in, const int* in_sizes, int n_in,
                              void* d_out, int out_size, void* d_ws, size_t ws_size,
                              hipStream_t stream)
{
    const float* x        = (const float*)d_in[0];   // (B,N,D)
    const float* features = (const float*)d_in[1];   // (B,D)
    const float* W_crd    = (const float*)d_in[2];   // (DM,K)
    const float* W_ftr    = (const float*)d_in[3];   // (DM,K)
    const float* pe_crd   = (const float*)d_in[4];   // (1,1,D,DM)
    const float* pe_ftr   = (const float*)d_in[5];   // (1,1,D,DM)
    // d_in[6] = k (constant 32), ignored

    float* out = (float*)d_out;                      // B*N*DM floats + 1 (pe_loss)

    float* xcrd  = (float*)d_ws;                     // 262144
    float* sqv   = xcrd + (size_t)B * N * D;         // 16384
    float* Tc    = sqv  + B * N;                     // 16384
    float* Tf    = Tc   + B * N;                     // 16384
    float* cbias = Tf   + B * N;                     // 256
    float* WcT   = cbias + DM;                       // 8192
    float* WfT   = WcT + KNN * DM;                   // 8192

    knn_prep<<<65, 256, 0, stream>>>(x, features, W_crd, W_ftr, pe_crd, pe_ftr,
                                     xcrd, sqv, Tc, Tf, WcT, WfT, cbias,
                                     out + (size_t)out_size - 1);
    knn_main<<<(B * N) / 4, 256, 0, stream>>>(xcrd, sqv, Tc, Tf,
                                              WcT, WfT, cbias, out);
}

// Round 2
// 313.645 us; speedup vs baseline: 1.0226x; 1.0226x over previous
//
#include <hip/hip_runtime.h>
#include <stdint.h>

// Problem constants
#define B 8
#define N 2048
#define D 16
#define KNN 32
#define DM 256
#define CAP 96   // tie-fixup cap; degenerate all-tie batches still rank correctly

// ---------------------------------------------------------------------------
// K1: fused prep (round-5 PROVEN, verbatim). Blocks 0..63: own-batch fp64
// stats, then per-point masked x_crd row -> xcrd, sq, Tc/Tf.
// Block 64: W transpose + pe bias/loss.
// ---------------------------------------------------------------------------
__global__ __launch_bounds__(256) void knn_prep(
    const float* __restrict__ x, const float* __restrict__ features,
    const float* __restrict__ Wc, const float* __restrict__ Wf,
    const float* __restrict__ pec, const float* __restrict__ pef,
    float* __restrict__ xcrd, float* __restrict__ sq,
    float* __restrict__ Tc, float* __restrict__ Tf,
    float* __restrict__ WcT, float* __restrict__ WfT,
    float* __restrict__ cbias, float* __restrict__ pe_loss_out)
{
    if (blockIdx.x == 64) {
        int dm = threadIdx.x;
        float cb = 0.f, al = 0.f;
#pragma unroll
        for (int p = 0; p < D; ++p)
            cb += pec[p * DM + dm] + pef[p * DM + dm];
#pragma unroll
        for (int p = 0; p < D; ++p)
            al += fabsf(pec[p * DM + dm]) + fabsf(pef[p * DM + dm]);
        cbias[dm] = cb;
#pragma unroll
        for (int k = 0; k < KNN; ++k) {
            WcT[k * DM + dm] = Wc[dm * KNN + k];
            WfT[k * DM + dm] = Wf[dm * KNN + k];
        }
        __shared__ float redf[256];
        redf[dm] = al; __syncthreads();
        for (int st = 128; st > 0; st >>= 1) {
            if (dm < st) redf[dm] += redf[dm + st];
            __syncthreads();
        }
        if (dm == 0) pe_loss_out[0] = redf[0];
        return;
    }

    int tid = threadIdx.x;
    int b = blockIdx.x >> 3;

    // ---- own-batch stats: 8 rows per thread, fp64 accumulate ----
    double ls[D], lq[D];
#pragma unroll
    for (int d = 0; d < D; ++d) { ls[d] = 0.0; lq[d] = 0.0; }
    for (int r = 0; r < 8; ++r) {
        const float* row = x + ((size_t)b * N + r * 256 + tid) * D;
#pragma unroll
        for (int d = 0; d < D; d += 4) {
            float4 v = *(const float4*)(row + d);
            double x0 = v.x, x1 = v.y, x2 = v.z, x3 = v.w;
            ls[d]   += x0; lq[d]   += x0 * x0;
            ls[d+1] += x1; lq[d+1] += x1 * x1;
            ls[d+2] += x2; lq[d+2] += x2 * x2;
            ls[d+3] += x3; lq[d+3] += x3 * x3;
        }
    }
#pragma unroll
    for (int d = 0; d < D; ++d) {
        double s = ls[d], q = lq[d];
#pragma unroll
        for (int st = 32; st >= 1; st >>= 1) {
            s += __shfl_xor(s, st, 64);
            q += __shfl_xor(q, st, 64);
        }
        ls[d] = s; lq[d] = q;
    }
    __shared__ double sred[4][2 * D];
    __shared__ float smean[32], sscale[32];
    int wave = tid >> 6, lane = tid & 63;
    if (lane == 0) {
#pragma unroll
        for (int d = 0; d < D; ++d) {
            sred[wave][d]     = ls[d];
            sred[wave][D + d] = lq[d];
        }
    }
    __syncthreads();
    if (tid < D) {
        int d = tid;
        double S = sred[0][d] + sred[1][d] + sred[2][d] + sred[3][d];
        double Q = sred[0][D+d] + sred[1][D+d] + sred[2][D+d] + sred[3][D+d];
        double mean = S / (double)N;
        double var  = (Q - S * S / (double)N) / (double)(N - 1);
        if (var < 0.0) var = 0.0;
        float stdv = (float)sqrt(var);
        float scl  = 1.0f / (stdv + 1e-5f);
        float scl0 = 1.0f / (0.0f + 1e-5f);
        bool mask = features[b * D + d] > 0.1f;
        smean [d]      = mask ? 0.0f : (float)mean;
        sscale[d]      = mask ? scl0 : scl;
        smean [16 + d] = mask ? (float)mean : 0.0f;
        sscale[16 + d] = mask ? scl : scl0;
    }
    __syncthreads();

    // ---- per-point processing (identical arithmetic to rounds 1-5) ----
    int t = blockIdx.x * 256 + tid;
    float tc = 0.f, tf = 0.f, s = 0.f;
    float row[D];
#pragma unroll
    for (int d = 0; d < D; ++d) {
        float xv = x[(size_t)t * D + d];
        bool mask = features[b * D + d] > 0.1f;
        float xc = mask ? 0.f : xv;
        float xf = mask ? xv : 0.f;
        row[d] = xc;
        s += xc * xc;                            // sequential, mirrors ref sq
        float vc = (xc - smean[d])      * sscale[d];
        vc = fminf(10.f, fmaxf(-10.f, vc));
        float vf = (xf - smean[16 + d]) * sscale[16 + d];
        vf = fminf(10.f, fmaxf(-10.f, vf));
        tc += vc; tf += vf;
    }
#pragma unroll
    for (int d = 0; d < D; d += 4)
        *(float4*)(xcrd + (size_t)t * D + d) =
            make_float4(row[d], row[d+1], row[d+2], row[d+3]);
    sq[t] = s; Tc[t] = tc; Tf[t] = tf;
}

// ---------------------------------------------------------------------------
// K2: FOUR waves per block (one query per wave) to lift occupancy past the
// 1-wave-workgroup residency cap (round 0: ~31% occ, VALUBusy 62%).
// ROUND-1 LESSON: __launch_bounds__(256,5) capped VGPR at ~102 < the ~100+
// live state (orig[32]+srt[32]+qx[16]) -> allocation collapsed to 48 with
// scratch spills (WRITE_SIZE 16->41 MB).  Bound relaxed to (256,4): cap 128
// VGPR, no spills; actual usage ~84-100 still yields 5-6 waves/SIMD.
// Wave-private LDS slices + wave-local lgkmcnt fences (no block barriers)
// keep the 4 waves independent for latency hiding.
// ---------------------------------------------------------------------------
#define WAVE_LDS_FENCE() do {                                   \
    asm volatile("s_waitcnt lgkmcnt(0)" ::: "memory");          \
    __builtin_amdgcn_sched_barrier(0);                          \
} while (0)

__global__ __launch_bounds__(256, 4) void knn_main(
    const float* __restrict__ xcrd, const float* __restrict__ sq,
    const float* __restrict__ Tc, const float* __restrict__ Tf,
    const float* __restrict__ WcT, const float* __restrict__ WfT,
    const float* __restrict__ cbias, float* __restrict__ out)
{
    __shared__ unsigned long long collect[4][CAP];
    __shared__ int sortedm[4][KNN];

    const int lane = threadIdx.x & 63;
    const int wid  = threadIdx.x >> 6;
    const int qid  = (blockIdx.x << 2) | wid;    // 0..16383
    const int b = qid >> 11;
    const int n = qid & (N - 1);

    unsigned long long* wcollect = collect[wid];
    int* wsorted = sortedm[wid];

    const float* xb  = xcrd + (size_t)b * N * D;
    const float* sqb = sq + b * N;

    // query row
    float qx[D];
#pragma unroll
    for (int d = 0; d < D; d += 4) {
        float4 v = *(const float4*)(xb + (size_t)n * D + d);
        qx[d] = v.x; qx[d+1] = v.y; qx[d+2] = v.z; qx[d+3] = v.w;
    }
    const float sqn = sqb[n];

    // ---- fill: round-5 distance arithmetic, byte-identical ----
    float orig[KNN], srt[KNN];
#pragma unroll
    for (int j = 0; j < KNN; ++j) {
        int m = j * 64 + lane;
        const float* xm = xb + (size_t)m * D;
        float4 v0 = *(const float4*)(xm);
        float4 v1 = *(const float4*)(xm + 4);
        float4 v2 = *(const float4*)(xm + 8);
        float4 v3 = *(const float4*)(xm + 12);
        float dot = 0.f;
        dot += qx[0]  * v0.x; dot += qx[1]  * v0.y;
        dot += qx[2]  * v0.z; dot += qx[3]  * v0.w;
        dot += qx[4]  * v1.x; dot += qx[5]  * v1.y;
        dot += qx[6]  * v1.z; dot += qx[7]  * v1.w;
        dot += qx[8]  * v2.x; dot += qx[9]  * v2.y;
        dot += qx[10] * v2.z; dot += qx[11] * v2.w;
        dot += qx[12] * v3.x; dot += qx[13] * v3.y;
        dot += qx[14] * v3.z; dot += qx[15] * v3.w;
        float d2 = sqn + sqb[m] - 2.0f * dot;
        float dist = fabsf(sqrtf(fmaxf(d2, 0.f)));   // fabs: -0 -> +0
        orig[j] = dist; srt[j] = dist;
    }

    // ---- per-lane bitonic sort (ascending) of the value copy ----
#pragma unroll
    for (int kk = 2; kk <= KNN; kk <<= 1) {
#pragma unroll
        for (int jj = kk >> 1; jj > 0; jj >>= 1) {
#pragma unroll
            for (int i = 0; i < KNN; ++i) {
                int l = i ^ jj;
                if (l > i) {
                    float a = srt[i], c2 = srt[l];
                    if ((i & kk) == 0) { srt[i] = fminf(a, c2); srt[l] = fmaxf(a, c2); }
                    else               { srt[i] = fmaxf(a, c2); srt[l] = fminf(a, c2); }
                }
            }
        }
    }

    // ---- 6 butterfly min-32 merge rounds (values only, duplicates ok) ----
#pragma unroll 1
    for (int s = 1; s <= 32; s <<= 1) {
#pragma unroll
        for (int i = 0; i < KNN / 2; ++i) {
            int r = KNN - 1 - i;
            float o_i = __shfl_xor(srt[r], s, 64);   // partner[31-i]
            float o_r = __shfl_xor(srt[i], s, 64);   // partner[31-r]
            srt[i] = fminf(srt[i], o_i);
            srt[r] = fminf(srt[r], o_r);
        }
#pragma unroll
        for (int jj = 16; jj >= 1; jj >>= 1) {
#pragma unroll
            for (int i = 0; i < KNN; ++i) {
                if ((i & jj) == 0) {
                    int l = i + jj;
                    float a = srt[i], c2 = srt[l];
                    srt[i] = fminf(a, c2);
                    srt[l] = fmaxf(a, c2);
                }
            }
        }
    }
    const float tau = srt[31];                   // exact 32nd smallest value

    // ---- tie-fixup: compact all dist <= tau in ascending global-index order ----
    const unsigned long long lmask = (1ULL << lane) - 1ULL;
    int base = 0;
#pragma unroll
    for (int j = 0; j < KNN; ++j) {
        bool f = (orig[j] <= tau);
        unsigned long long mk = __ballot(f);
        if (f) {
            int pos = base + (int)__popcll(mk & lmask);
            if (pos < CAP)
                wcollect[pos] =
                    (((unsigned long long)__float_as_uint(orig[j])) << 11)
                    | (unsigned)(j * 64 + lane);
        }
        base += (int)__popcll(mk);
    }
    int T = base < CAP ? base : CAP;             // wave-uniform, >= 32
    WAVE_LDS_FENCE();                            // all lanes' ds_writes drained

    // ---- rank the T collected items (keys globally unique) ----
#pragma unroll 1
    for (int slot = 0; slot < 2; ++slot) {
        int i = lane + slot * 64;
        if (i < T) {
            unsigned long long mk = wcollect[i];
            int rank = 0;
#pragma unroll 1
            for (int t2 = 0; t2 < T; ++t2)
                rank += (wcollect[t2] < mk) ? 1 : 0;
            if (rank < KNN)
                wsorted[rank] = (int)(mk & 2047u);
        }
    }
    WAVE_LDS_FENCE();                            // wsorted visible to own wave

    // ---- matvec: ranked top-32 ----
    float acc[4] = {0.f, 0.f, 0.f, 0.f};
    const float* Tcb = Tc + b * N;
    const float* Tfb = Tf + b * N;
    const float Tcn = Tcb[n], Tfn = Tfb[n];

#pragma unroll
    for (int k = 0; k < KNN; ++k) {
        int wm = wsorted[k];
        float ak = Tcb[wm] - Tcn;
        float bk = Tfb[wm] - Tfn;
        const float* wc = WcT + k * DM + lane;
        const float* wf = WfT + k * DM + lane;
#pragma unroll
        for (int q = 0; q < 4; ++q)
            acc[q] += wc[q * 64] * ak + wf[q * 64] * bk;
    }

    size_t obase = (size_t)qid * DM + lane;
#pragma unroll
    for (int q = 0; q < 4; ++q)
        out[obase + q * 64] = acc[q] + cbias[lane + q * 64];
}

// ---------------------------------------------------------------------------
extern "C" void kernel_launch(void* const* d_in, const int* in_sizes, int n_in,
                              void* d_out, int out_size, void* d_ws, size_t ws_size,
                              hipStream_t stream)
{
    const float* x        = (const float*)d_in[0];   // (B,N,D)
    const float* features = (const float*)d_in[1];   // (B,D)
    const float* W_crd    = (const float*)d_in[2];   // (DM,K)
    const float* W_ftr    = (const float*)d_in[3];   // (DM,K)
    const float* pe_crd   = (const float*)d_in[4];   // (1,1,D,DM)
    const float* pe_ftr   = (const float*)d_in[5];   // (1,1,D,DM)
    // d_in[6] = k (constant 32), ignored

    float* out = (float*)d_out;                      // B*N*DM floats + 1 (pe_loss)

    float* xcrd  = (float*)d_ws;                     // 262144
    float* sqv   = xcrd + (size_t)B * N * D;         // 16384
    float* Tc    = sqv  + B * N;                     // 16384
    float* Tf    = Tc   + B * N;                     // 16384
    float* cbias = Tf   + B * N;                     // 256
    float* WcT   = cbias + DM;                       // 8192
    float* WfT   = WcT + KNN * DM;                   // 8192

    knn_prep<<<65, 256, 0, stream>>>(x, features, W_crd, W_ftr, pe_crd, pe_ftr,
                                     xcrd, sqv, Tc, Tf, WcT, WfT, cbias,
                                     out + (size_t)out_size - 1);
    knn_main<<<(B * N) / 4, 256, 0, stream>>>(xcrd, sqv, Tc, Tf,
                                              WcT, WfT, cbias, out);
}

// Round 3
// 301.294 us; speedup vs baseline: 1.0645x; 1.0410x over previous
//
#include <hip/hip_runtime.h>
#include <stdint.h>

// Problem constants
#define B 8
#define N 2048
#define D 16
#define KNN 32
#define DM 256
#define CAP 96   // tie-fixup cap; degenerate all-tie batches still rank correctly

// ---------------------------------------------------------------------------
// K1: fused prep (round-5 PROVEN, verbatim). Blocks 0..63: own-batch fp64
// stats, then per-point masked x_crd row -> xcrd, sq, Tc/Tf.
// Block 64: W transpose + pe bias/loss.
// ---------------------------------------------------------------------------
__global__ __launch_bounds__(256) void knn_prep(
    const float* __restrict__ x, const float* __restrict__ features,
    const float* __restrict__ Wc, const float* __restrict__ Wf,
    const float* __restrict__ pec, const float* __restrict__ pef,
    float* __restrict__ xcrd, float* __restrict__ sq,
    float* __restrict__ Tc, float* __restrict__ Tf,
    float* __restrict__ WcT, float* __restrict__ WfT,
    float* __restrict__ cbias, float* __restrict__ pe_loss_out)
{
    if (blockIdx.x == 64) {
        int dm = threadIdx.x;
        float cb = 0.f, al = 0.f;
#pragma unroll
        for (int p = 0; p < D; ++p)
            cb += pec[p * DM + dm] + pef[p * DM + dm];
#pragma unroll
        for (int p = 0; p < D; ++p)
            al += fabsf(pec[p * DM + dm]) + fabsf(pef[p * DM + dm]);
        cbias[dm] = cb;
#pragma unroll
        for (int k = 0; k < KNN; ++k) {
            WcT[k * DM + dm] = Wc[dm * KNN + k];
            WfT[k * DM + dm] = Wf[dm * KNN + k];
        }
        __shared__ float redf[256];
        redf[dm] = al; __syncthreads();
        for (int st = 128; st > 0; st >>= 1) {
            if (dm < st) redf[dm] += redf[dm + st];
            __syncthreads();
        }
        if (dm == 0) pe_loss_out[0] = redf[0];
        return;
    }

    int tid = threadIdx.x;
    int b = blockIdx.x >> 3;

    // ---- own-batch stats: 8 rows per thread, fp64 accumulate ----
    double ls[D], lq[D];
#pragma unroll
    for (int d = 0; d < D; ++d) { ls[d] = 0.0; lq[d] = 0.0; }
    for (int r = 0; r < 8; ++r) {
        const float* row = x + ((size_t)b * N + r * 256 + tid) * D;
#pragma unroll
        for (int d = 0; d < D; d += 4) {
            float4 v = *(const float4*)(row + d);
            double x0 = v.x, x1 = v.y, x2 = v.z, x3 = v.w;
            ls[d]   += x0; lq[d]   += x0 * x0;
            ls[d+1] += x1; lq[d+1] += x1 * x1;
            ls[d+2] += x2; lq[d+2] += x2 * x2;
            ls[d+3] += x3; lq[d+3] += x3 * x3;
        }
    }
#pragma unroll
    for (int d = 0; d < D; ++d) {
        double s = ls[d], q = lq[d];
#pragma unroll
        for (int st = 32; st >= 1; st >>= 1) {
            s += __shfl_xor(s, st, 64);
            q += __shfl_xor(q, st, 64);
        }
        ls[d] = s; lq[d] = q;
    }
    __shared__ double sred[4][2 * D];
    __shared__ float smean[32], sscale[32];
    int wave = tid >> 6, lane = tid & 63;
    if (lane == 0) {
#pragma unroll
        for (int d = 0; d < D; ++d) {
            sred[wave][d]     = ls[d];
            sred[wave][D + d] = lq[d];
        }
    }
    __syncthreads();
    if (tid < D) {
        int d = tid;
        double S = sred[0][d] + sred[1][d] + sred[2][d] + sred[3][d];
        double Q = sred[0][D+d] + sred[1][D+d] + sred[2][D+d] + sred[3][D+d];
        double mean = S / (double)N;
        double var  = (Q - S * S / (double)N) / (double)(N - 1);
        if (var < 0.0) var = 0.0;
        float stdv = (float)sqrt(var);
        float scl  = 1.0f / (stdv + 1e-5f);
        float scl0 = 1.0f / (0.0f + 1e-5f);
        bool mask = features[b * D + d] > 0.1f;
        smean [d]      = mask ? 0.0f : (float)mean;
        sscale[d]      = mask ? scl0 : scl;
        smean [16 + d] = mask ? (float)mean : 0.0f;
        sscale[16 + d] = mask ? scl : scl0;
    }
    __syncthreads();

    // ---- per-point processing (identical arithmetic to rounds 1-5) ----
    int t = blockIdx.x * 256 + tid;
    float tc = 0.f, tf = 0.f, s = 0.f;
    float row[D];
#pragma unroll
    for (int d = 0; d < D; ++d) {
        float xv = x[(size_t)t * D + d];
        bool mask = features[b * D + d] > 0.1f;
        float xc = mask ? 0.f : xv;
        float xf = mask ? xv : 0.f;
        row[d] = xc;
        s += xc * xc;                            // sequential, mirrors ref sq
        float vc = (xc - smean[d])      * sscale[d];
        vc = fminf(10.f, fmaxf(-10.f, vc));
        float vf = (xf - smean[16 + d]) * sscale[16 + d];
        vf = fminf(10.f, fmaxf(-10.f, vf));
        tc += vc; tf += vf;
    }
#pragma unroll
    for (int d = 0; d < D; d += 4)
        *(float4*)(xcrd + (size_t)t * D + d) =
            make_float4(row[d], row[d+1], row[d+2], row[d+3]);
    sq[t] = s; Tc[t] = tc; Tf[t] = tf;
}

// ---------------------------------------------------------------------------
// K2: FOUR waves per block (one query per wave) to lift occupancy past the
// 1-wave-workgroup residency cap (round 0: 1-wave blocks, ~31% occ,
// VALUBusy 62%, 193 us).
// ROUND-1/2 LESSON: a second __launch_bounds__ arg >=4 makes the allocator
// chase the 8-waves/EU step (VGPR squeezed to 64/48) and spill the ~85-reg
// live set (orig[32]+srt[32]) -> WRITE_SIZE 16.4->30-41 MB scratch traffic,
// VALUBusy DOWN to 47%.  Fix: plain __launch_bounds__(256) (same as
// knn_prep, never spills) -> natural ~84-96 VGPR allocation, spill-free,
// 4 waves/SIMD occupancy from the <=128-VGPR step.
// Wave-private LDS slices + wave-local lgkmcnt fences (no block barriers)
// keep the 4 waves independent for latency hiding.
// ---------------------------------------------------------------------------
#define WAVE_LDS_FENCE() do {                                   \
    asm volatile("s_waitcnt lgkmcnt(0)" ::: "memory");          \
    __builtin_amdgcn_sched_barrier(0);                          \
} while (0)

__global__ __launch_bounds__(256) void knn_main(
    const float* __restrict__ xcrd, const float* __restrict__ sq,
    const float* __restrict__ Tc, const float* __restrict__ Tf,
    const float* __restrict__ WcT, const float* __restrict__ WfT,
    const float* __restrict__ cbias, float* __restrict__ out)
{
    __shared__ unsigned long long collect[4][CAP];
    __shared__ int sortedm[4][KNN];

    const int lane = threadIdx.x & 63;
    const int wid  = threadIdx.x >> 6;
    const int qid  = (blockIdx.x << 2) | wid;    // 0..16383
    const int b = qid >> 11;
    const int n = qid & (N - 1);

    unsigned long long* wcollect = collect[wid];
    int* wsorted = sortedm[wid];

    const float* xb  = xcrd + (size_t)b * N * D;
    const float* sqb = sq + b * N;

    // query row
    float qx[D];
#pragma unroll
    for (int d = 0; d < D; d += 4) {
        float4 v = *(const float4*)(xb + (size_t)n * D + d);
        qx[d] = v.x; qx[d+1] = v.y; qx[d+2] = v.z; qx[d+3] = v.w;
    }
    const float sqn = sqb[n];

    // ---- fill: round-5 distance arithmetic, byte-identical ----
    float orig[KNN], srt[KNN];
#pragma unroll
    for (int j = 0; j < KNN; ++j) {
        int m = j * 64 + lane;
        const float* xm = xb + (size_t)m * D;
        float4 v0 = *(const float4*)(xm);
        float4 v1 = *(const float4*)(xm + 4);
        float4 v2 = *(const float4*)(xm + 8);
        float4 v3 = *(const float4*)(xm + 12);
        float dot = 0.f;
        dot += qx[0]  * v0.x; dot += qx[1]  * v0.y;
        dot += qx[2]  * v0.z; dot += qx[3]  * v0.w;
        dot += qx[4]  * v1.x; dot += qx[5]  * v1.y;
        dot += qx[6]  * v1.z; dot += qx[7]  * v1.w;
        dot += qx[8]  * v2.x; dot += qx[9]  * v2.y;
        dot += qx[10] * v2.z; dot += qx[11] * v2.w;
        dot += qx[12] * v3.x; dot += qx[13] * v3.y;
        dot += qx[14] * v3.z; dot += qx[15] * v3.w;
        float d2 = sqn + sqb[m] - 2.0f * dot;
        float dist = fabsf(sqrtf(fmaxf(d2, 0.f)));   // fabs: -0 -> +0
        orig[j] = dist; srt[j] = dist;
    }

    // ---- per-lane bitonic sort (ascending) of the value copy ----
#pragma unroll
    for (int kk = 2; kk <= KNN; kk <<= 1) {
#pragma unroll
        for (int jj = kk >> 1; jj > 0; jj >>= 1) {
#pragma unroll
            for (int i = 0; i < KNN; ++i) {
                int l = i ^ jj;
                if (l > i) {
                    float a = srt[i], c2 = srt[l];
                    if ((i & kk) == 0) { srt[i] = fminf(a, c2); srt[l] = fmaxf(a, c2); }
                    else               { srt[i] = fmaxf(a, c2); srt[l] = fminf(a, c2); }
                }
            }
        }
    }

    // ---- 6 butterfly min-32 merge rounds (values only, duplicates ok) ----
#pragma unroll 1
    for (int s = 1; s <= 32; s <<= 1) {
#pragma unroll
        for (int i = 0; i < KNN / 2; ++i) {
            int r = KNN - 1 - i;
            float o_i = __shfl_xor(srt[r], s, 64);   // partner[31-i]
            float o_r = __shfl_xor(srt[i], s, 64);   // partner[31-r]
            srt[i] = fminf(srt[i], o_i);
            srt[r] = fminf(srt[r], o_r);
        }
#pragma unroll
        for (int jj = 16; jj >= 1; jj >>= 1) {
#pragma unroll
            for (int i = 0; i < KNN; ++i) {
                if ((i & jj) == 0) {
                    int l = i + jj;
                    float a = srt[i], c2 = srt[l];
                    srt[i] = fminf(a, c2);
                    srt[l] = fmaxf(a, c2);
                }
            }
        }
    }
    const float tau = srt[31];                   // exact 32nd smallest value

    // ---- tie-fixup: compact all dist <= tau in ascending global-index order ----
    const unsigned long long lmask = (1ULL << lane) - 1ULL;
    int base = 0;
#pragma unroll
    for (int j = 0; j < KNN; ++j) {
        bool f = (orig[j] <= tau);
        unsigned long long mk = __ballot(f);
        if (f) {
            int pos = base + (int)__popcll(mk & lmask);
            if (pos < CAP)
                wcollect[pos] =
                    (((unsigned long long)__float_as_uint(orig[j])) << 11)
                    | (unsigned)(j * 64 + lane);
        }
        base += (int)__popcll(mk);
    }
    int T = base < CAP ? base : CAP;             // wave-uniform, >= 32
    WAVE_LDS_FENCE();                            // all lanes' ds_writes drained

    // ---- rank the T collected items (keys globally unique) ----
#pragma unroll 1
    for (int slot = 0; slot < 2; ++slot) {
        int i = lane + slot * 64;
        if (i < T) {
            unsigned long long mk = wcollect[i];
            int rank = 0;
#pragma unroll 1
            for (int t2 = 0; t2 < T; ++t2)
                rank += (wcollect[t2] < mk) ? 1 : 0;
            if (rank < KNN)
                wsorted[rank] = (int)(mk & 2047u);
        }
    }
    WAVE_LDS_FENCE();                            // wsorted visible to own wave

    // ---- matvec: ranked top-32 ----
    float acc[4] = {0.f, 0.f, 0.f, 0.f};
    const float* Tcb = Tc + b * N;
    const float* Tfb = Tf + b * N;
    const float Tcn = Tcb[n], Tfn = Tfb[n];

#pragma unroll
    for (int k = 0; k < KNN; ++k) {
        int wm = wsorted[k];
        float ak = Tcb[wm] - Tcn;
        float bk = Tfb[wm] - Tfn;
        const float* wc = WcT + k * DM + lane;
        const float* wf = WfT + k * DM + lane;
#pragma unroll
        for (int q = 0; q < 4; ++q)
            acc[q] += wc[q * 64] * ak + wf[q * 64] * bk;
    }

    size_t obase = (size_t)qid * DM + lane;
#pragma unroll
    for (int q = 0; q < 4; ++q)
        out[obase + q * 64] = acc[q] + cbias[lane + q * 64];
}

// ---------------------------------------------------------------------------
extern "C" void kernel_launch(void* const* d_in, const int* in_sizes, int n_in,
                              void* d_out, int out_size, void* d_ws, size_t ws_size,
                              hipStream_t stream)
{
    const float* x        = (const float*)d_in[0];   // (B,N,D)
    const float* features = (const float*)d_in[1];   // (B,D)
    const float* W_crd    = (const float*)d_in[2];   // (DM,K)
    const float* W_ftr    = (const float*)d_in[3];   // (DM,K)
    const float* pe_crd   = (const float*)d_in[4];   // (1,1,D,DM)
    const float* pe_ftr   = (const float*)d_in[5];   // (1,1,D,DM)
    // d_in[6] = k (constant 32), ignored

    float* out = (float*)d_out;                      // B*N*DM floats + 1 (pe_loss)

    float* xcrd  = (float*)d_ws;                     // 262144
    float* sqv   = xcrd + (size_t)B * N * D;         // 16384
    float* Tc    = sqv  + B * N;                     // 16384
    float* Tf    = Tc   + B * N;                     // 16384
    float* cbias = Tf   + B * N;                     // 256
    float* WcT   = cbias + DM;                       // 8192
    float* WfT   = WcT + KNN * DM;                   // 8192

    knn_prep<<<65, 256, 0, stream>>>(x, features, W_crd, W_ftr, pe_crd, pe_ftr,
                                     xcrd, sqv, Tc, Tf, WcT, WfT, cbias,
                                     out + (size_t)out_size - 1);
    knn_main<<<(B * N) / 4, 256, 0, stream>>>(xcrd, sqv, Tc, Tf,
                                              WcT, WfT, cbias, out);
}

// Round 4
// 290.871 us; speedup vs baseline: 1.1027x; 1.0358x over previous
//
#include <hip/hip_runtime.h>
#include <stdint.h>

// Problem constants
#define B 8
#define N 2048
#define D 16
#define KNN 32
#define DM 256
#define CAP 256  // candidate cap; approx-tau yields ~44 candidates (z~30 margin)

// ---------------------------------------------------------------------------
// K1: fused prep (round-5 PROVEN, verbatim). Blocks 0..63: own-batch fp64
// stats, then per-point masked x_crd row -> xcrd, sq, Tc/Tf.
// Block 64: W transpose + pe bias/loss.
// ---------------------------------------------------------------------------
__global__ __launch_bounds__(256) void knn_prep(
    const float* __restrict__ x, const float* __restrict__ features,
    const float* __restrict__ Wc, const float* __restrict__ Wf,
    const float* __restrict__ pec, const float* __restrict__ pef,
    float* __restrict__ xcrd, float* __restrict__ sq,
    float* __restrict__ Tc, float* __restrict__ Tf,
    float* __restrict__ WcT, float* __restrict__ WfT,
    float* __restrict__ cbias, float* __restrict__ pe_loss_out)
{
    if (blockIdx.x == 64) {
        int dm = threadIdx.x;
        float cb = 0.f, al = 0.f;
#pragma unroll
        for (int p = 0; p < D; ++p)
            cb += pec[p * DM + dm] + pef[p * DM + dm];
#pragma unroll
        for (int p = 0; p < D; ++p)
            al += fabsf(pec[p * DM + dm]) + fabsf(pef[p * DM + dm]);
        cbias[dm] = cb;
#pragma unroll
        for (int k = 0; k < KNN; ++k) {
            WcT[k * DM + dm] = Wc[dm * KNN + k];
            WfT[k * DM + dm] = Wf[dm * KNN + k];
        }
        __shared__ float redf[256];
        redf[dm] = al; __syncthreads();
        for (int st = 128; st > 0; st >>= 1) {
            if (dm < st) redf[dm] += redf[dm + st];
            __syncthreads();
        }
        if (dm == 0) pe_loss_out[0] = redf[0];
        return;
    }

    int tid = threadIdx.x;
    int b = blockIdx.x >> 3;

    // ---- own-batch stats: 8 rows per thread, fp64 accumulate ----
    double ls[D], lq[D];
#pragma unroll
    for (int d = 0; d < D; ++d) { ls[d] = 0.0; lq[d] = 0.0; }
    for (int r = 0; r < 8; ++r) {
        const float* row = x + ((size_t)b * N + r * 256 + tid) * D;
#pragma unroll
        for (int d = 0; d < D; d += 4) {
            float4 v = *(const float4*)(row + d);
            double x0 = v.x, x1 = v.y, x2 = v.z, x3 = v.w;
            ls[d]   += x0; lq[d]   += x0 * x0;
            ls[d+1] += x1; lq[d+1] += x1 * x1;
            ls[d+2] += x2; lq[d+2] += x2 * x2;
            ls[d+3] += x3; lq[d+3] += x3 * x3;
        }
    }
#pragma unroll
    for (int d = 0; d < D; ++d) {
        double s = ls[d], q = lq[d];
#pragma unroll
        for (int st = 32; st >= 1; st >>= 1) {
            s += __shfl_xor(s, st, 64);
            q += __shfl_xor(q, st, 64);
        }
        ls[d] = s; lq[d] = q;
    }
    __shared__ double sred[4][2 * D];
    __shared__ float smean[32], sscale[32];
    int wave = tid >> 6, lane = tid & 63;
    if (lane == 0) {
#pragma unroll
        for (int d = 0; d < D; ++d) {
            sred[wave][d]     = ls[d];
            sred[wave][D + d] = lq[d];
        }
    }
    __syncthreads();
    if (tid < D) {
        int d = tid;
        double S = sred[0][d] + sred[1][d] + sred[2][d] + sred[3][d];
        double Q = sred[0][D+d] + sred[1][D+d] + sred[2][D+d] + sred[3][D+d];
        double mean = S / (double)N;
        double var  = (Q - S * S / (double)N) / (double)(N - 1);
        if (var < 0.0) var = 0.0;
        float stdv = (float)sqrt(var);
        float scl  = 1.0f / (stdv + 1e-5f);
        float scl0 = 1.0f / (0.0f + 1e-5f);
        bool mask = features[b * D + d] > 0.1f;
        smean [d]      = mask ? 0.0f : (float)mean;
        sscale[d]      = mask ? scl0 : scl;
        smean [16 + d] = mask ? (float)mean : 0.0f;
        sscale[16 + d] = mask ? scl : scl0;
    }
    __syncthreads();

    // ---- per-point processing (identical arithmetic to rounds 1-5) ----
    int t = blockIdx.x * 256 + tid;
    float tc = 0.f, tf = 0.f, s = 0.f;
    float row[D];
#pragma unroll
    for (int d = 0; d < D; ++d) {
        float xv = x[(size_t)t * D + d];
        bool mask = features[b * D + d] > 0.1f;
        float xc = mask ? 0.f : xv;
        float xf = mask ? xv : 0.f;
        row[d] = xc;
        s += xc * xc;                            // sequential, mirrors ref sq
        float vc = (xc - smean[d])      * sscale[d];
        vc = fminf(10.f, fmaxf(-10.f, vc));
        float vf = (xf - smean[16 + d]) * sscale[16 + d];
        vf = fminf(10.f, fmaxf(-10.f, vf));
        tc += vc; tf += vf;
    }
#pragma unroll
    for (int d = 0; d < D; d += 4)
        *(float4*)(xcrd + (size_t)t * D + d) =
            make_float4(row[d], row[d+1], row[d+2], row[d+3]);
    sq[t] = s; Tc[t] = tc; Tf[t] = tf;
}

// ---------------------------------------------------------------------------
// K2: ROUND-0 PROVEN STRUCTURE (one 64-thread block per query; rounds 1-3
// showed multi-wave workgroups do NOT raise residency: ~10 waves/CU in all
// configs, and they ran slower).  This round replaces only the tau
// computation: the ~1830-op bitonic sort + 6 merge/clean rounds is replaced
// by a 140-op APPROXIMATE upper bound.
//
// Correctness: downstream tie-fixup + ranking selects the exact top-32 by
// (dist,idx) from ANY candidate superset; tau only needs
// count(dist<=tau) in [32, CAP].  tau_hat = 32nd-smallest of the 64
// per-lane minima satisfies count>=32 (each of the 32 lanes with
// min<=tau_hat contributes >=1 element) and therefore tau_hat >= exact
// 32nd-smallest -> all true top-32 are collected.  Candidate count for
// iid data ~ Binomial(2048, 1-2^(-1/32)) ~= 44 +/- 7; CAP=256 gives ~30
// sigma of headroom.  Output is bit-identical to the exact-tau kernel.
// Bonus: srt[32] eliminated -> ~32 fewer live VGPRs -> crosses the 64-VGPR
// occupancy step.
// ---------------------------------------------------------------------------
__global__ __launch_bounds__(64, 2) void knn_main(
    const float* __restrict__ xcrd, const float* __restrict__ sq,
    const float* __restrict__ Tc, const float* __restrict__ Tf,
    const float* __restrict__ WcT, const float* __restrict__ WfT,
    const float* __restrict__ cbias, float* __restrict__ out)
{
    __shared__ unsigned long long collect[CAP];
    __shared__ int sortedm[KNN];

    const int lane = threadIdx.x;
    const int qid  = blockIdx.x;                 // 0..16383
    const int b = qid >> 11;
    const int n = qid & (N - 1);

    const float* xb  = xcrd + (size_t)b * N * D;
    const float* sqb = sq + b * N;

    // query row
    float qx[D];
#pragma unroll
    for (int d = 0; d < D; d += 4) {
        float4 v = *(const float4*)(xb + (size_t)n * D + d);
        qx[d] = v.x; qx[d+1] = v.y; qx[d+2] = v.z; qx[d+3] = v.w;
    }
    const float sqn = sqb[n];

    // ---- fill: round-5 distance arithmetic, byte-identical ----
    float orig[KNN];
#pragma unroll
    for (int j = 0; j < KNN; ++j) {
        int m = j * 64 + lane;
        const float* xm = xb + (size_t)m * D;
        float4 v0 = *(const float4*)(xm);
        float4 v1 = *(const float4*)(xm + 4);
        float4 v2 = *(const float4*)(xm + 8);
        float4 v3 = *(const float4*)(xm + 12);
        float dot = 0.f;
        dot += qx[0]  * v0.x; dot += qx[1]  * v0.y;
        dot += qx[2]  * v0.z; dot += qx[3]  * v0.w;
        dot += qx[4]  * v1.x; dot += qx[5]  * v1.y;
        dot += qx[6]  * v1.z; dot += qx[7]  * v1.w;
        dot += qx[8]  * v2.x; dot += qx[9]  * v2.y;
        dot += qx[10] * v2.z; dot += qx[11] * v2.w;
        dot += qx[12] * v3.x; dot += qx[13] * v3.y;
        dot += qx[14] * v3.z; dot += qx[15] * v3.w;
        float d2 = sqn + sqb[m] - 2.0f * dot;
        float dist = fabsf(sqrtf(fmaxf(d2, 0.f)));   // fabs: -0 -> +0
        orig[j] = dist;
    }

    // ---- approx tau: 32nd-smallest of the 64 per-lane minima ----
    // per-lane min tree (31 ops, log depth)
    float red[16];
#pragma unroll
    for (int i = 0; i < 16; ++i) red[i] = fminf(orig[i], orig[i + 16]);
#pragma unroll
    for (int st = 8; st >= 1; st >>= 1)
#pragma unroll
        for (int i = 0; i < st; ++i) red[i] = fminf(red[i], red[i + st]);
    float v = red[0];
    // cross-lane bitonic sort of 64 lane-minima, ascending by lane index
#pragma unroll
    for (int k = 2; k <= 64; k <<= 1) {
#pragma unroll
        for (int j = k >> 1; j >= 1; j >>= 1) {
            float o = __shfl_xor(v, j, 64);
            bool lower = (lane & j) == 0;        // this lane is low half of pair
            bool up    = (lane & k) == 0;        // ascending block
            v = (lower == up) ? fminf(v, o) : fmaxf(v, o);
        }
    }
    const float tau = __shfl(v, 31, 64);         // >= exact 32nd smallest

    // ---- tie-fixup: compact all dist <= tau in ascending global-index order ----
    const unsigned long long lmask = (1ULL << lane) - 1ULL;
    int base = 0;
#pragma unroll
    for (int j = 0; j < KNN; ++j) {
        bool f = (orig[j] <= tau);
        unsigned long long mk = __ballot(f);
        if (f) {
            int pos = base + (int)__popcll(mk & lmask);
            if (pos < CAP)
                collect[pos] =
                    (((unsigned long long)__float_as_uint(orig[j])) << 11)
                    | (unsigned)(j * 64 + lane);
        }
        base += (int)__popcll(mk);
    }
    int T = base < CAP ? base : CAP;             // wave-uniform, >= 32
    __syncthreads();

    // ---- rank the T collected items (keys globally unique) ----
#pragma unroll 1
    for (int slot = 0; slot < CAP / 64; ++slot) {
        int i = lane + slot * 64;
        if (i < T) {
            unsigned long long mk = collect[i];
            int rank = 0;
#pragma unroll 1
            for (int t2 = 0; t2 < T; ++t2)
                rank += (collect[t2] < mk) ? 1 : 0;
            if (rank < KNN)
                sortedm[rank] = (int)(mk & 2047u);
        }
    }
    __syncthreads();

    // ---- matvec: ranked top-32 ----
    float acc[4] = {0.f, 0.f, 0.f, 0.f};
    const float* Tcb = Tc + b * N;
    const float* Tfb = Tf + b * N;
    const float Tcn = Tcb[n], Tfn = Tfb[n];

#pragma unroll
    for (int k = 0; k < KNN; ++k) {
        int wm = sortedm[k];
        float ak = Tcb[wm] - Tcn;
        float bk = Tfb[wm] - Tfn;
        const float* wc = WcT + k * DM + lane;
        const float* wf = WfT + k * DM + lane;
#pragma unroll
        for (int q = 0; q < 4; ++q)
            acc[q] += wc[q * 64] * ak + wf[q * 64] * bk;
    }

    size_t obase = (size_t)qid * DM + lane;
#pragma unroll
    for (int q = 0; q < 4; ++q)
        out[obase + q * 64] = acc[q] + cbias[lane + q * 64];
}

// ---------------------------------------------------------------------------
extern "C" void kernel_launch(void* const* d_in, const int* in_sizes, int n_in,
                              void* d_out, int out_size, void* d_ws, size_t ws_size,
                              hipStream_t stream)
{
    const float* x        = (const float*)d_in[0];   // (B,N,D)
    const float* features = (const float*)d_in[1];   // (B,D)
    const float* W_crd    = (const float*)d_in[2];   // (DM,K)
    const float* W_ftr    = (const float*)d_in[3];   // (DM,K)
    const float* pe_crd   = (const float*)d_in[4];   // (1,1,D,DM)
    const float* pe_ftr   = (const float*)d_in[5];   // (1,1,D,DM)
    // d_in[6] = k (constant 32), ignored

    float* out = (float*)d_out;                      // B*N*DM floats + 1 (pe_loss)

    float* xcrd  = (float*)d_ws;                     // 262144
    float* sqv   = xcrd + (size_t)B * N * D;         // 16384
    float* Tc    = sqv  + B * N;                     // 16384
    float* Tf    = Tc   + B * N;                     // 16384
    float* cbias = Tf   + B * N;                     // 256
    float* WcT   = cbias + DM;                       // 8192
    float* WfT   = WcT + KNN * DM;                   // 8192

    knn_prep<<<65, 256, 0, stream>>>(x, features, W_crd, W_ftr, pe_crd, pe_ftr,
                                     xcrd, sqv, Tc, Tf, WcT, WfT, cbias,
                                     out + (size_t)out_size - 1);
    knn_main<<<B * N, 64, 0, stream>>>(xcrd, sqv, Tc, Tf,
                                       WcT, WfT, cbias, out);
}

// Round 5
// 201.737 us; speedup vs baseline: 1.5899x; 1.4418x over previous
//
#include <hip/hip_runtime.h>
#include <stdint.h>

// Problem constants
#define B 8
#define N 2048
#define D 16
#define KNN 32
#define DM 256
#define CAP 256  // candidate cap; approx-tau yields ~44 candidates (z~30 margin)

// ---------------------------------------------------------------------------
// K1: fused prep. Identical arithmetic to the proven version; the ONLY
// change is the xcrd store layout: [B][N][D] row-major -> [B][D][N]
// TRANSPOSED, so knn_main's fill loads are lane-contiguous (coalesced).
// Block 64: W transpose + pe bias/loss (verbatim).
// ---------------------------------------------------------------------------
__global__ __launch_bounds__(256) void knn_prep(
    const float* __restrict__ x, const float* __restrict__ features,
    const float* __restrict__ Wc, const float* __restrict__ Wf,
    const float* __restrict__ pec, const float* __restrict__ pef,
    float* __restrict__ xcrdT, float* __restrict__ sq,
    float* __restrict__ Tc, float* __restrict__ Tf,
    float* __restrict__ WcT, float* __restrict__ WfT,
    float* __restrict__ cbias, float* __restrict__ pe_loss_out)
{
    if (blockIdx.x == 64) {
        int dm = threadIdx.x;
        float cb = 0.f, al = 0.f;
#pragma unroll
        for (int p = 0; p < D; ++p)
            cb += pec[p * DM + dm] + pef[p * DM + dm];
#pragma unroll
        for (int p = 0; p < D; ++p)
            al += fabsf(pec[p * DM + dm]) + fabsf(pef[p * DM + dm]);
        cbias[dm] = cb;
#pragma unroll
        for (int k = 0; k < KNN; ++k) {
            WcT[k * DM + dm] = Wc[dm * KNN + k];
            WfT[k * DM + dm] = Wf[dm * KNN + k];
        }
        __shared__ float redf[256];
        redf[dm] = al; __syncthreads();
        for (int st = 128; st > 0; st >>= 1) {
            if (dm < st) redf[dm] += redf[dm + st];
            __syncthreads();
        }
        if (dm == 0) pe_loss_out[0] = redf[0];
        return;
    }

    int tid = threadIdx.x;
    int b = blockIdx.x >> 3;

    // ---- own-batch stats: 8 rows per thread, fp64 accumulate ----
    double ls[D], lq[D];
#pragma unroll
    for (int d = 0; d < D; ++d) { ls[d] = 0.0; lq[d] = 0.0; }
    for (int r = 0; r < 8; ++r) {
        const float* row = x + ((size_t)b * N + r * 256 + tid) * D;
#pragma unroll
        for (int d = 0; d < D; d += 4) {
            float4 v = *(const float4*)(row + d);
            double x0 = v.x, x1 = v.y, x2 = v.z, x3 = v.w;
            ls[d]   += x0; lq[d]   += x0 * x0;
            ls[d+1] += x1; lq[d+1] += x1 * x1;
            ls[d+2] += x2; lq[d+2] += x2 * x2;
            ls[d+3] += x3; lq[d+3] += x3 * x3;
        }
    }
#pragma unroll
    for (int d = 0; d < D; ++d) {
        double s = ls[d], q = lq[d];
#pragma unroll
        for (int st = 32; st >= 1; st >>= 1) {
            s += __shfl_xor(s, st, 64);
            q += __shfl_xor(q, st, 64);
        }
        ls[d] = s; lq[d] = q;
    }
    __shared__ double sred[4][2 * D];
    __shared__ float smean[32], sscale[32];
    int wave = tid >> 6, lane = tid & 63;
    if (lane == 0) {
#pragma unroll
        for (int d = 0; d < D; ++d) {
            sred[wave][d]     = ls[d];
            sred[wave][D + d] = lq[d];
        }
    }
    __syncthreads();
    if (tid < D) {
        int d = tid;
        double S = sred[0][d] + sred[1][d] + sred[2][d] + sred[3][d];
        double Q = sred[0][D+d] + sred[1][D+d] + sred[2][D+d] + sred[3][D+d];
        double mean = S / (double)N;
        double var  = (Q - S * S / (double)N) / (double)(N - 1);
        if (var < 0.0) var = 0.0;
        float stdv = (float)sqrt(var);
        float scl  = 1.0f / (stdv + 1e-5f);
        float scl0 = 1.0f / (0.0f + 1e-5f);
        bool mask = features[b * D + d] > 0.1f;
        smean [d]      = mask ? 0.0f : (float)mean;
        sscale[d]      = mask ? scl0 : scl;
        smean [16 + d] = mask ? (float)mean : 0.0f;
        sscale[16 + d] = mask ? scl : scl0;
    }
    __syncthreads();

    // ---- per-point processing (identical arithmetic; transposed store) ----
    int t = blockIdx.x * 256 + tid;
    int nn = t & (N - 1);
    float tc = 0.f, tf = 0.f, s = 0.f;
    float row[D];
#pragma unroll
    for (int d = 0; d < D; ++d) {
        float xv = x[(size_t)t * D + d];
        bool mask = features[b * D + d] > 0.1f;
        float xc = mask ? 0.f : xv;
        float xf = mask ? xv : 0.f;
        row[d] = xc;
        s += xc * xc;                            // sequential, mirrors ref sq
        float vc = (xc - smean[d])      * sscale[d];
        vc = fminf(10.f, fmaxf(-10.f, vc));
        float vf = (xf - smean[16 + d]) * sscale[16 + d];
        vf = fminf(10.f, fmaxf(-10.f, vf));
        tc += vc; tf += vf;
    }
#pragma unroll
    for (int d = 0; d < D; ++d)                  // coalesced per-d across wave
        xcrdT[((size_t)b * D + d) * N + nn] = row[d];
    sq[t] = s; Tc[t] = tc; Tf[t] = tf;
}

// ---------------------------------------------------------------------------
// K2: round-0 structure (one 64-thread block per query), two latency fixes:
//
// (1) FILL reads the TRANSPOSED xcrdT [D][N]: per row-group j, 16
//     lane-contiguous dword loads (256 B/instruction, ~4 cache lines) vs the
//     old stride-64B dwordx4 pattern (64 lines/instruction).  Dot product
//     accumulates in the same sequential d-order -> bit-identical dist.
// (2) RANK: the serial LDS scan (~T x 130 cy of exposed ds_read latency) is
//     replaced, for the common T<=64 case, by an in-wave 64-key u64 bitonic
//     sort (21 pipelined compare-exchange stages).  Keys are globally unique
//     (dist_bits<<11 | m), so after the ascending sort lane k holds the k-th
//     smallest key; lanes 0..31 write sortedm directly.  T>64 (degenerate
//     mass ties) falls back to the original serial ranking - identical
//     behavior.  tau = 32nd-smallest of the 64 lane-minima (proven round 4):
//     >= exact 32nd distance, so the candidate set is always a superset of
//     the true top-32; downstream exact (dist,idx) ranking makes the output
//     bit-identical to the exact-tau kernel.
// ---------------------------------------------------------------------------
__global__ __launch_bounds__(64, 2) void knn_main(
    const float* __restrict__ xcrdT, const float* __restrict__ sq,
    const float* __restrict__ Tc, const float* __restrict__ Tf,
    const float* __restrict__ WcT, const float* __restrict__ WfT,
    const float* __restrict__ cbias, float* __restrict__ out)
{
    __shared__ unsigned long long collect[CAP];
    __shared__ int sortedm[KNN];

    const int lane = threadIdx.x;
    const int qid  = blockIdx.x;                 // 0..16383
    const int b = qid >> 11;
    const int n = qid & (N - 1);

    const float* xbT = xcrdT + (size_t)b * D * N;
    const float* sqb = sq + b * N;

    // query row (uniform scalar loads from the transposed layout)
    float qx[D];
#pragma unroll
    for (int d = 0; d < D; ++d)
        qx[d] = xbT[(size_t)d * N + n];
    const float sqn = sqb[n];

    // ---- fill: coalesced transposed loads; same sequential dot order ----
    float orig[KNN];
#pragma unroll
    for (int j = 0; j < KNN; ++j) {
        int m = j * 64 + lane;
        float val[D];
#pragma unroll
        for (int d = 0; d < D; ++d)
            val[d] = xbT[(size_t)d * N + m];
        float dot = 0.f;
#pragma unroll
        for (int d = 0; d < D; ++d)
            dot += qx[d] * val[d];
        float d2 = sqn + sqb[m] - 2.0f * dot;
        orig[j] = fabsf(sqrtf(fmaxf(d2, 0.f)));  // fabs: -0 -> +0
    }

    // ---- approx tau: 32nd-smallest of the 64 per-lane minima ----
    float red[16];
#pragma unroll
    for (int i = 0; i < 16; ++i) red[i] = fminf(orig[i], orig[i + 16]);
#pragma unroll
    for (int st = 8; st >= 1; st >>= 1)
#pragma unroll
        for (int i = 0; i < st; ++i) red[i] = fminf(red[i], red[i + st]);
    float v = red[0];
#pragma unroll
    for (int k = 2; k <= 64; k <<= 1) {
#pragma unroll
        for (int j = k >> 1; j >= 1; j >>= 1) {
            float o = __shfl_xor(v, j, 64);
            bool lower = (lane & j) == 0;
            bool up    = (lane & k) == 0;
            v = (lower == up) ? fminf(v, o) : fmaxf(v, o);
        }
    }
    const float tau = __shfl(v, 31, 64);         // >= exact 32nd smallest

    // ---- tie-fixup: compact all dist <= tau in ascending global-index order ----
    const unsigned long long lmask = (1ULL << lane) - 1ULL;
    int base = 0;
#pragma unroll
    for (int j = 0; j < KNN; ++j) {
        bool f = (orig[j] <= tau);
        unsigned long long mk = __ballot(f);
        if (f) {
            int pos = base + (int)__popcll(mk & lmask);
            if (pos < CAP)
                collect[pos] =
                    (((unsigned long long)__float_as_uint(orig[j])) << 11)
                    | (unsigned)(j * 64 + lane);
        }
        base += (int)__popcll(mk);
    }
    int T = base < CAP ? base : CAP;             // wave-uniform, >= 32
    __syncthreads();

    if (T <= 64) {
        // ---- fast path: in-wave bitonic sort of up to 64 unique keys ----
        unsigned long long key = (lane < T) ? collect[lane] : ~0ULL;
#pragma unroll
        for (int k = 2; k <= 64; k <<= 1) {
#pragma unroll
            for (int j = k >> 1; j >= 1; j >>= 1) {
                unsigned long long o = __shfl_xor(key, j, 64);
                bool lower = (lane & j) == 0;
                bool up    = (lane & k) == 0;
                unsigned long long mn = (o < key) ? o : key;
                unsigned long long mx = (o < key) ? key : o;
                key = (lower == up) ? mn : mx;
            }
        }
        if (lane < KNN)
            sortedm[lane] = (int)(key & 2047u);
    } else {
        // ---- slow path (degenerate mass ties): original exact ranking ----
#pragma unroll 1
        for (int slot = 0; slot < CAP / 64; ++slot) {
            int i = lane + slot * 64;
            if (i < T) {
                unsigned long long mk = collect[i];
                int rank = 0;
#pragma unroll 4
                for (int t2 = 0; t2 < T; ++t2)
                    rank += (collect[t2] < mk) ? 1 : 0;
                if (rank < KNN)
                    sortedm[rank] = (int)(mk & 2047u);
            }
        }
    }
    __syncthreads();

    // ---- matvec: ranked top-32 ----
    float acc[4] = {0.f, 0.f, 0.f, 0.f};
    const float* Tcb = Tc + b * N;
    const float* Tfb = Tf + b * N;
    const float Tcn = Tcb[n], Tfn = Tfb[n];

#pragma unroll
    for (int k = 0; k < KNN; ++k) {
        int wm = sortedm[k];
        float ak = Tcb[wm] - Tcn;
        float bk = Tfb[wm] - Tfn;
        const float* wc = WcT + k * DM + lane;
        const float* wf = WfT + k * DM + lane;
#pragma unroll
        for (int q = 0; q < 4; ++q)
            acc[q] += wc[q * 64] * ak + wf[q * 64] * bk;
    }

    size_t obase = (size_t)qid * DM + lane;
#pragma unroll
    for (int q = 0; q < 4; ++q)
        out[obase + q * 64] = acc[q] + cbias[lane + q * 64];
}

// ---------------------------------------------------------------------------
extern "C" void kernel_launch(void* const* d_in, const int* in_sizes, int n_in,
                              void* d_out, int out_size, void* d_ws, size_t ws_size,
                              hipStream_t stream)
{
    const float* x        = (const float*)d_in[0];   // (B,N,D)
    const float* features = (const float*)d_in[1];   // (B,D)
    const float* W_crd    = (const float*)d_in[2];   // (DM,K)
    const float* W_ftr    = (const float*)d_in[3];   // (DM,K)
    const float* pe_crd   = (const float*)d_in[4];   // (1,1,D,DM)
    const float* pe_ftr   = (const float*)d_in[5];   // (1,1,D,DM)
    // d_in[6] = k (constant 32), ignored

    float* out = (float*)d_out;                      // B*N*DM floats + 1 (pe_loss)

    float* xcrdT = (float*)d_ws;                     // 262144 (B*D*N, transposed)
    float* sqv   = xcrdT + (size_t)B * N * D;        // 16384
    float* Tc    = sqv  + B * N;                     // 16384
    float* Tf    = Tc   + B * N;                     // 16384
    float* cbias = Tf   + B * N;                     // 256
    float* WcT   = cbias + DM;                       // 8192
    float* WfT   = WcT + KNN * DM;                   // 8192

    knn_prep<<<65, 256, 0, stream>>>(x, features, W_crd, W_ftr, pe_crd, pe_ftr,
                                     xcrdT, sqv, Tc, Tf, WcT, WfT, cbias,
                                     out + (size_t)out_size - 1);
    knn_main<<<B * N, 64, 0, stream>>>(xcrdT, sqv, Tc, Tf,
                                       WcT, WfT, cbias, out);
}